// Round 3
// baseline (128.056 us; speedup 1.0000x reference)
//
#include <hip/hip_runtime.h>
#include <hip/hip_bf16.h>
#include <math.h>

#define NNODES 4096
#define FDIM 128
#define HDIM 3
#define BGRAPH 8
#define GAT_ALPHA 0.2f

typedef int v4i __attribute__((ext_vector_type(4)));

// ---------------------------------------------------------------------------
// Kernel A: per-node Wh = emb[i,:]@W  (128x3), e_src[i], e_dst[i].
// One wave per node row, 4 waves/block. Packs tbl[i] = (Wh0,Wh1,Wh2,e_dst).
// ---------------------------------------------------------------------------
__global__ __launch_bounds__(256) void wh_kernel(
    const float* __restrict__ emb, const float* __restrict__ W,
    const float* __restrict__ a,
    float4* __restrict__ tbl, float* __restrict__ esrc) {
    int wid = threadIdx.x >> 6, lane = threadIdx.x & 63;
    int i = blockIdx.x * 4 + wid;
    const float2 ev = *reinterpret_cast<const float2*>(emb + (size_t)i * FDIM + lane * 2);
    int t0 = lane * 2;
    float wh0 = ev.x * W[t0 * 3 + 0] + ev.y * W[(t0 + 1) * 3 + 0];
    float wh1 = ev.x * W[t0 * 3 + 1] + ev.y * W[(t0 + 1) * 3 + 1];
    float wh2 = ev.x * W[t0 * 3 + 2] + ev.y * W[(t0 + 1) * 3 + 2];
    for (int off = 32; off >= 1; off >>= 1) {
        wh0 += __shfl_xor(wh0, off);
        wh1 += __shfl_xor(wh1, off);
        wh2 += __shfl_xor(wh2, off);
    }
    if (lane == 0) {
        float es = wh0 * a[0] + wh1 * a[1] + wh2 * a[2];
        float ed = wh0 * a[3] + wh1 * a[4] + wh2 * a[5];
        tbl[i] = make_float4(wh0, wh1, wh2, ed);
        esrc[i] = es;
    }
}

// ---------------------------------------------------------------------------
// Kernel B: masked softmax + PV. ONE WAVE PER NODE ROW i, ALL 8 GRAPHS AT
// ONCE: the score w[i,j] = exp(lrelu(es_i + ed_j) - m_i) is graph-independent
// (graphs share emb/W/a), so compute it once per j and apply 8 adj masks.
// Per T-iter: 8 independent 1KB adj loads (deep MLP), 4 shared ds_read_b128.
// LDS table swizzled j -> (j&3)*1024 + (j>>2): lane-consecutive = conflict-free.
// Shift m = lrelu(es_i + dmax) >= true row max (lrelu monotone) -> pure sums.
// ---------------------------------------------------------------------------
__global__ __launch_bounds__(512, 4) void attn_kernel(
    const int* __restrict__ adj, const float4* __restrict__ tbl,
    const float* __restrict__ esrc, float* __restrict__ hout) {
    __shared__ float4 ltbl[NNODES];  // 64 KB -> 2 blocks/CU
    __shared__ float4 red[8];
    int tid = threadIdx.x;
    int wid = tid >> 6, lane = tid & 63;

    // stage table + block-reduce {sum_j Wh, max_j e_dst}
    float s0 = 0.f, s1 = 0.f, s2 = 0.f, mx = -INFINITY;
    for (int k = tid; k < NNODES; k += 512) {
        float4 v = tbl[k];
        ltbl[(k & 3) * 1024 + (k >> 2)] = v;
        s0 += v.x; s1 += v.y; s2 += v.z; mx = fmaxf(mx, v.w);
    }
    for (int off = 32; off >= 1; off >>= 1) {
        s0 += __shfl_xor(s0, off);
        s1 += __shfl_xor(s1, off);
        s2 += __shfl_xor(s2, off);
        mx = fmaxf(mx, __shfl_xor(mx, off));
    }
    if (lane == 0) red[wid] = make_float4(s0, s1, s2, mx);
    __syncthreads();
    if (tid < 8) {
        float4 v = red[tid];
        for (int off = 4; off >= 1; off >>= 1) {
            v.x += __shfl_xor(v.x, off);
            v.y += __shfl_xor(v.y, off);
            v.z += __shfl_xor(v.z, off);
            v.w = fmaxf(v.w, __shfl_xor(v.w, off));
        }
        if (tid == 0) red[0] = v;
    }
    __syncthreads();
    const float4 st = red[0];   // (sum Wh0, sum Wh1, sum Wh2, dmax)
    const float L2E = 1.4426950408889634f;

    int i = blockIdx.x * 8 + wid;          // 512 blocks * 8 waves = 4096 rows
    float es = esrc[i];
    float m = es + st.w;
    m = fmaxf(m, GAT_ALPHA * m);           // lrelu(es + dmax) = row max bound
    float bias = -m * L2E;

    // per-graph adj row pointers (g fully unrolled -> static, stays in regs)
    const v4i* ap[BGRAPH];
    #pragma unroll
    for (int g = 0; g < BGRAPH; ++g)
        ap[g] = reinterpret_cast<const v4i*>(adj + ((size_t)g * NNODES + i) * NNODES);

    float sw[BGRAPH], a0[BGRAPH], a1[BGRAPH], a2[BGRAPH];
    #pragma unroll
    for (int g = 0; g < BGRAPH; ++g) { sw[g] = 0.f; a0[g] = 0.f; a1[g] = 0.f; a2[g] = 0.f; }

    #pragma unroll 1
    for (int T = 0; T < 16; ++T) {
        int base = T * 64 + lane;
        v4i av[BGRAPH];
        #pragma unroll
        for (int g = 0; g < BGRAPH; ++g)
            av[g] = __builtin_nontemporal_load(ap[g] + base);  // 8x1KB in flight
        #pragma unroll
        for (int c = 0; c < 4; ++c) {
            float4 tv = ltbl[c * 1024 + base];   // j = 4*base + c, shared by all g
            float t = es + tv.w;
            float x = fmaxf(t, GAT_ALPHA * t);
            float w = __builtin_amdgcn_exp2f(x * L2E + bias);
            #pragma unroll
            for (int g = 0; g < BGRAPH; ++g) {
                float wg = (av[g][c] > 0) ? w : 0.f;
                sw[g] += wg;
                a0[g] += wg * tv.x;
                a1[g] += wg * tv.y;
                a2[g] += wg * tv.z;
            }
        }
    }

    // cross-lane merge: pure sums thanks to precomputed shift
    #pragma unroll
    for (int g = 0; g < BGRAPH; ++g) {
        for (int off = 32; off >= 1; off >>= 1) {
            sw[g] += __shfl_xor(sw[g], off);
            a0[g] += __shfl_xor(a0[g], off);
            a1[g] += __shfl_xor(a1[g], off);
            a2[g] += __shfl_xor(a2[g], off);
        }
    }
    if (lane == 0) {
        #pragma unroll
        for (int g = 0; g < BGRAPH; ++g) {
            float h0, h1, h2;
            if (sw[g] > 0.f) {
                h0 = a0[g] / sw[g]; h1 = a1[g] / sw[g]; h2 = a2[g] / sw[g];
            } else {  // fully-masked row: softmax degenerates to uniform
                h0 = st.x * (1.f / NNODES);
                h1 = st.y * (1.f / NNODES);
                h2 = st.z * (1.f / NNODES);
            }
            h0 = h0 > 0.f ? h0 : expf(h0) - 1.f;   // elu
            h1 = h1 > 0.f ? h1 : expf(h1) - 1.f;
            h2 = h2 > 0.f ? h2 : expf(h2) - 1.f;
            float* hp = hout + ((size_t)g * NNODES + i) * 3;
            hp[0] = h0; hp[1] = h1; hp[2] = h2;
        }
    }
}

// ---------------------------------------------------------------------------
// Kernel C: out[b,o] = elu_h[b,:] . fc1_w[o,:] + fc1_b[o].  800 blocks.
// ---------------------------------------------------------------------------
__global__ void fc_kernel(const float* __restrict__ h, const float* __restrict__ w,
                          const float* __restrict__ bias, float* __restrict__ out) {
    int bo = blockIdx.x;
    int bg = bo / 100, o = bo % 100;
    const float* hrow = h + (size_t)bg * (NNODES * HDIM);
    const float* wrow = w + (size_t)o * (NNODES * HDIM);
    int tid = threadIdx.x;
    float p = 0.f;
    for (int k = tid; k < NNODES * HDIM; k += 256) p += hrow[k] * wrow[k];
    __shared__ float sh[256];
    sh[tid] = p;
    __syncthreads();
    for (int off = 128; off >= 1; off >>= 1) {
        if (tid < off) sh[tid] += sh[tid + off];
        __syncthreads();
    }
    if (tid == 0) out[bo] = sh[0] + bias[o];
}

extern "C" void kernel_launch(void* const* d_in, const int* in_sizes, int n_in,
                              void* d_out, int out_size, void* d_ws, size_t ws_size,
                              hipStream_t stream) {
    const int*   adj  = (const int*)d_in[0];
    const float* emb  = (const float*)d_in[1];
    const float* W    = (const float*)d_in[2];
    const float* a    = (const float*)d_in[3];
    const float* fc1w = (const float*)d_in[4];
    const float* fc1b = (const float*)d_in[5];
    float* out = (float*)d_out;

    char* ws = (char*)d_ws;
    float4* tbl  = (float4*)ws;                        // 64 KB
    float*  esrc = (float*)(ws + 65536);               // 16 KB
    float*  hout = (float*)(ws + 65536 + 16384);       // 8*4096*3*4 = 384 KB

    wh_kernel<<<NNODES / 4, 256, 0, stream>>>(emb, W, a, tbl, esrc);
    attn_kernel<<<512, 512, 0, stream>>>(adj, tbl, esrc, hout);
    fc_kernel<<<BGRAPH * 100, 256, 0, stream>>>(hout, fc1w, fc1b, out);
}

// Round 4
// 103.260 us; speedup vs baseline: 1.2401x; 1.2401x over previous
//
#include <hip/hip_runtime.h>
#include <hip/hip_bf16.h>
#include <math.h>

#define NNODES 4096
#define FDIM 128
#define HDIM 3
#define BGRAPH 8
#define GAT_ALPHA 0.2f

typedef int v4i __attribute__((ext_vector_type(4)));

// ---------------------------------------------------------------------------
// Kernel A: per-node Wh = emb[i,:]@W  (128x3), e_src[i], e_dst[i].
// One wave per node row, 4 waves/block. Packs tbl[i] = (Wh0,Wh1,Wh2,e_dst).
// ---------------------------------------------------------------------------
__global__ __launch_bounds__(256) void wh_kernel(
    const float* __restrict__ emb, const float* __restrict__ W,
    const float* __restrict__ a,
    float4* __restrict__ tbl, float* __restrict__ esrc) {
    int wid = threadIdx.x >> 6, lane = threadIdx.x & 63;
    int i = blockIdx.x * 4 + wid;
    const float2 ev = *reinterpret_cast<const float2*>(emb + (size_t)i * FDIM + lane * 2);
    int t0 = lane * 2;
    float wh0 = ev.x * W[t0 * 3 + 0] + ev.y * W[(t0 + 1) * 3 + 0];
    float wh1 = ev.x * W[t0 * 3 + 1] + ev.y * W[(t0 + 1) * 3 + 1];
    float wh2 = ev.x * W[t0 * 3 + 2] + ev.y * W[(t0 + 1) * 3 + 2];
    for (int off = 32; off >= 1; off >>= 1) {
        wh0 += __shfl_xor(wh0, off);
        wh1 += __shfl_xor(wh1, off);
        wh2 += __shfl_xor(wh2, off);
    }
    if (lane == 0) {
        float es = wh0 * a[0] + wh1 * a[1] + wh2 * a[2];
        float ed = wh0 * a[3] + wh1 * a[4] + wh2 * a[5];
        tbl[i] = make_float4(wh0, wh1, wh2, ed);
        esrc[i] = es;
    }
}

// ---------------------------------------------------------------------------
// Kernel B: masked softmax + PV. One wave per node row i; FOUR sequential
// graph-PAIRS (G=2 blocking): the score w[i,j] = exp(lrelu(es_i+ed_j) - m_i)
// is graph-independent, so each computed w feeds 2 adj masks. G=2 (not 8)
// keeps live registers ~60 — no spills under the 128-VGPR cap (R2 lesson).
// Per T-iter: 2 independent 1KB adj loads, 4 shared ds_read_b128 (swizzled
// j -> (j&3)*1024 + (j>>2): lane-consecutive = conflict-free).
// Shift m = lrelu(es_i + dmax) >= true row max (lrelu monotone) -> pure sums.
// ---------------------------------------------------------------------------
__global__ __launch_bounds__(512, 4) void attn_kernel(
    const int* __restrict__ adj, const float4* __restrict__ tbl,
    const float* __restrict__ esrc, float* __restrict__ hout) {
    __shared__ float4 ltbl[NNODES];  // 64 KB -> 2 blocks/CU
    __shared__ float4 red[8];
    int tid = threadIdx.x;
    int wid = tid >> 6, lane = tid & 63;

    // stage table + block-reduce {sum_j Wh, max_j e_dst}
    float s0 = 0.f, s1 = 0.f, s2 = 0.f, mx = -INFINITY;
    for (int k = tid; k < NNODES; k += 512) {
        float4 v = tbl[k];
        ltbl[(k & 3) * 1024 + (k >> 2)] = v;
        s0 += v.x; s1 += v.y; s2 += v.z; mx = fmaxf(mx, v.w);
    }
    for (int off = 32; off >= 1; off >>= 1) {
        s0 += __shfl_xor(s0, off);
        s1 += __shfl_xor(s1, off);
        s2 += __shfl_xor(s2, off);
        mx = fmaxf(mx, __shfl_xor(mx, off));
    }
    if (lane == 0) red[wid] = make_float4(s0, s1, s2, mx);
    __syncthreads();
    if (tid < 8) {
        float4 v = red[tid];
        for (int off = 4; off >= 1; off >>= 1) {
            v.x += __shfl_xor(v.x, off);
            v.y += __shfl_xor(v.y, off);
            v.z += __shfl_xor(v.z, off);
            v.w = fmaxf(v.w, __shfl_xor(v.w, off));
        }
        if (tid == 0) red[0] = v;
    }
    __syncthreads();
    const float4 st = red[0];   // (sum Wh0, sum Wh1, sum Wh2, dmax)
    const float L2E = 1.4426950408889634f;

    int i = blockIdx.x * 8 + wid;          // 512 blocks * 8 waves = 4096 rows
    float es = esrc[i];
    float m = es + st.w;
    m = fmaxf(m, GAT_ALPHA * m);           // lrelu(es + dmax) = row max bound
    float bias = -m * L2E;
    const size_t GSTRIDE = (size_t)NNODES * NNODES / 4;  // one graph, in v4i units

    #pragma unroll 1
    for (int p = 0; p < 4; ++p) {          // graph pair {2p, 2p+1}
        const v4i* ap0 = reinterpret_cast<const v4i*>(adj + ((size_t)(2 * p) * NNODES + i) * NNODES);
        const v4i* ap1 = ap0 + GSTRIDE;

        float sA = 0.f, xA = 0.f, yA = 0.f, zA = 0.f;
        float sB = 0.f, xB = 0.f, yB = 0.f, zB = 0.f;
        #pragma unroll 2
        for (int T = 0; T < 16; ++T) {
            int base = T * 64 + lane;
            v4i av0 = __builtin_nontemporal_load(ap0 + base);
            v4i av1 = __builtin_nontemporal_load(ap1 + base);
            #pragma unroll
            for (int c = 0; c < 4; ++c) {
                float4 tv = ltbl[c * 1024 + base];   // j = 4*base + c
                float t = es + tv.w;
                float x = fmaxf(t, GAT_ALPHA * t);
                float w = __builtin_amdgcn_exp2f(x * L2E + bias);
                float w0 = (av0[c] > 0) ? w : 0.f;
                float w1 = (av1[c] > 0) ? w : 0.f;
                sA += w0; xA += w0 * tv.x; yA += w0 * tv.y; zA += w0 * tv.z;
                sB += w1; xB += w1 * tv.x; yB += w1 * tv.y; zB += w1 * tv.z;
            }
        }
        // cross-lane merge: pure sums thanks to precomputed shift
        for (int off = 32; off >= 1; off >>= 1) {
            sA += __shfl_xor(sA, off); xA += __shfl_xor(xA, off);
            yA += __shfl_xor(yA, off); zA += __shfl_xor(zA, off);
            sB += __shfl_xor(sB, off); xB += __shfl_xor(xB, off);
            yB += __shfl_xor(yB, off); zB += __shfl_xor(zB, off);
        }
        if (lane == 0) {
            #pragma unroll
            for (int q = 0; q < 2; ++q) {
                float sw = q ? sB : sA;
                float h0, h1, h2;
                if (sw > 0.f) {
                    h0 = (q ? xB : xA) / sw;
                    h1 = (q ? yB : yA) / sw;
                    h2 = (q ? zB : zA) / sw;
                } else {  // fully-masked row: softmax degenerates to uniform
                    h0 = st.x * (1.f / NNODES);
                    h1 = st.y * (1.f / NNODES);
                    h2 = st.z * (1.f / NNODES);
                }
                h0 = h0 > 0.f ? h0 : expf(h0) - 1.f;   // elu
                h1 = h1 > 0.f ? h1 : expf(h1) - 1.f;
                h2 = h2 > 0.f ? h2 : expf(h2) - 1.f;
                float* hp = hout + ((size_t)(2 * p + q) * NNODES + i) * 3;
                hp[0] = h0; hp[1] = h1; hp[2] = h2;
            }
        }
    }
}

// ---------------------------------------------------------------------------
// Kernel C: out[b,o] = elu_h[b,:] . fc1_w[o,:] + fc1_b[o].  800 blocks.
// float4 loads: 12288 floats = 12 float4 per thread at 256 threads.
// ---------------------------------------------------------------------------
__global__ __launch_bounds__(256) void fc_kernel(
    const float* __restrict__ h, const float* __restrict__ w,
    const float* __restrict__ bias, float* __restrict__ out) {
    int bo = blockIdx.x;
    int bg = bo / 100, o = bo % 100;
    const float4* hrow = reinterpret_cast<const float4*>(h + (size_t)bg * (NNODES * HDIM));
    const float4* wrow = reinterpret_cast<const float4*>(w + (size_t)o * (NNODES * HDIM));
    int tid = threadIdx.x;
    float p = 0.f;
    #pragma unroll
    for (int k = 0; k < 12; ++k) {
        float4 hv = hrow[k * 256 + tid];
        float4 wv = wrow[k * 256 + tid];
        p += hv.x * wv.x + hv.y * wv.y + hv.z * wv.z + hv.w * wv.w;
    }
    __shared__ float sh[256];
    sh[tid] = p;
    __syncthreads();
    for (int off = 128; off >= 1; off >>= 1) {
        if (tid < off) sh[tid] += sh[tid + off];
        __syncthreads();
    }
    if (tid == 0) out[bo] = sh[0] + bias[o];
}

extern "C" void kernel_launch(void* const* d_in, const int* in_sizes, int n_in,
                              void* d_out, int out_size, void* d_ws, size_t ws_size,
                              hipStream_t stream) {
    const int*   adj  = (const int*)d_in[0];
    const float* emb  = (const float*)d_in[1];
    const float* W    = (const float*)d_in[2];
    const float* a    = (const float*)d_in[3];
    const float* fc1w = (const float*)d_in[4];
    const float* fc1b = (const float*)d_in[5];
    float* out = (float*)d_out;

    char* ws = (char*)d_ws;
    float4* tbl  = (float4*)ws;                        // 64 KB
    float*  esrc = (float*)(ws + 65536);               // 16 KB
    float*  hout = (float*)(ws + 65536 + 16384);       // 8*4096*3*4 = 384 KB

    wh_kernel<<<NNODES / 4, 256, 0, stream>>>(emb, W, a, tbl, esrc);
    attn_kernel<<<512, 512, 0, stream>>>(adj, tbl, esrc, hout);
    fc_kernel<<<BGRAPH * 100, 256, 0, stream>>>(hout, fc1w, fc1b, out);
}